// Round 1
// 374.276 us; speedup vs baseline: 1.0544x; 1.0544x over previous
//
#include <hip/hip_runtime.h>
#include <hip/hip_bf16.h>
#include <stdint.h>

// NODE forest — MFMA path. The 48 per-row selector dots are a GEMM
// z = W(48x64) . X^T per 64-row wave; computed on the matrix pipe via a
// 2-term bf16 split (hi+lo, 3 product terms), which removes ~41 us of FP32
// VALU FMA work (no fp32 MFMA on CDNA4, so bf16-split is the only escape).
// Exactness: worst-case |z_bf16split - z_np| <= 3*2^-18 * sum|x_i w_i| (~1.2e-4)
// + f32 reorder (~1e-5). Bits with |z - tau| < kMarginB (2e-3, ~15x bound) are
// re-derived with the bit-exact numpy-order dot (np_exact_dot), as before.
// Layouts (verified guide, m89/m92/m93):
//   D = A(MxK).B(KxN): D[row][col]: col=lane&15, row=(lane>>4)*4+reg
//   A: row=lane&15, k=8*(lane>>4)+i (8 contiguous)   B: col=lane&15, same k
// We compute C = W . X^T (M=48 d's, N=64 x-rows, K=64), so lane q=(lane>>4),
// r16=(lane&15) holds, per col-tile ct, 12 logits {d = rt*16+q*4+i} of x-row
// ct*16+r16. Two shfl_xor OR-butterflies (16,32) assemble each row's full
// 48-bit mask on its owner lane (row == lane within the wave).

typedef float f32x2 __attribute__((ext_vector_type(2)));
typedef float f32x4 __attribute__((ext_vector_type(4)));
typedef short short8 __attribute__((ext_vector_type(8)));

static constexpr int   kBlocks  = 4096;            // x4 waves x64 lanes = 1M rows
static constexpr float kTau     = 1.5f * 0x1p-24f; // f32 sigmoid dead-zone threshold
static constexpr float kMarginB = 2e-3f;           // ~15x analytic worst-case bf16-split drift

// Bit-exact replica of numpy's baseline-SIMD einsum f32 order (unchanged, r5-verified).
__device__ __noinline__ float np_exact_dot(const float* __restrict__ xs,
                                           const float* __restrict__ w) {
#pragma clang fp contract(off)
  float s[4];
#pragma unroll
  for (int L = 0; L < 4; ++L) {
    float t = xs[12 + L] * w[12 + L];
    t = xs[8 + L] * w[8 + L] + t;
    t = xs[4 + L] * w[4 + L] + t;
    t = xs[0 + L] * w[0 + L] + t;
#pragma unroll
    for (int j = 1; j < 4; ++j) {
      const int o = 16 * j;
      t = xs[o + 12 + L] * w[o + 12 + L] + t;
      t = xs[o +  8 + L] * w[o +  8 + L] + t;
      t = xs[o +  4 + L] * w[o +  4 + L] + t;
      t = xs[o +  0 + L] * w[o +  0 + L] + t;
    }
    s[L] = t;
  }
  return (s[0] + s[1]) + (s[2] + s[3]);   // SSE3 hadd pairing
}

__device__ __forceinline__ short bf16_hi(float v, float& hf) {
  const __hip_bfloat16 h = __float2bfloat16(v);   // RNE
  hf = __bfloat162float(h);
  return __builtin_bit_cast(short, h);
}
__device__ __forceinline__ short bf16_rn(float v) {
  return __builtin_bit_cast(short, __float2bfloat16(v));
}

__global__ __launch_bounds__(256) void forest_mfma(
    const float* __restrict__ x,     // [B,64]
    const float* __restrict__ Wsel,  // [48,64]
    const float* __restrict__ bsel,  // [48]
    const float* __restrict__ leaf,  // [8,64,2]
    const float* __restrict__ fcw,   // [2,16]
    const float* __restrict__ fcb,   // [2]
    float* __restrict__ out)         // [B,2]
{
  __shared__ f32x2 lleaf[512];
  ((f32x4*)lleaf)[threadIdx.x] = ((const f32x4*)leaf)[threadIdx.x];
  __syncthreads();

  const int lane = threadIdx.x & 63;
  const int wave = threadIdx.x >> 6;
  const int q    = lane >> 4;    // 0..3 : k-chunk group / d sub-offset
  const int r16  = lane & 15;    // 0..15
  const int rowbase = (blockIdx.x * 4 + wave) * 64;

  // ---- W fragments (A-operand), split hi/lo bf16. Lane: row=rt*16+r16,
  //      k = kh*32 + q*8 + i. Loaded once; L1-broadcast across waves.
  short8 whi[3][2], wlo[3][2];
#pragma unroll
  for (int rt = 0; rt < 3; ++rt) {
#pragma unroll
    for (int kh = 0; kh < 2; ++kh) {
      const float* wp = Wsel + (rt * 16 + r16) * 64 + kh * 32 + q * 8;
      const f32x4 w0 = *(const f32x4*)wp;
      const f32x4 w1 = *(const f32x4*)(wp + 4);
      short8 hi, lo;
#pragma unroll
      for (int i = 0; i < 4; ++i) {
        float hf;
        short h = bf16_hi(w0[i], hf);
        hi[i] = h;     lo[i]     = bf16_rn(w0[i] - hf);
        h = bf16_hi(w1[i], hf);
        hi[4 + i] = h; lo[4 + i] = bf16_rn(w1[i] - hf);
      }
      whi[rt][kh] = hi; wlo[rt][kh] = lo;
    }
  }

  // ---- tau - bias for this lane's 12 d's: d = rt*16 + q*4 + i
  f32x4 taub[3];
#pragma unroll
  for (int rt = 0; rt < 3; ++rt) {
    const f32x4 bs = *(const f32x4*)(bsel + rt * 16 + q * 4);
    f32x4 t;
#pragma unroll
    for (int i = 0; i < 4; ++i) t[i] = kTau - bs[i];
    taub[rt] = t;
  }

  // ---- X fragment loads (B-operand): lane reads x-row ct*16+r16,
  //      8 f32 at k = q*8 and k = 32+q*8. Prefetched one ct ahead.
  const float* xw = x + (size_t)(rowbase + r16) * 64 + q * 8;
  f32x4 a0 = *(const f32x4*)(xw);
  f32x4 a1 = *(const f32x4*)(xw + 4);
  f32x4 a2 = *(const f32x4*)(xw + 32);
  f32x4 a3 = *(const f32x4*)(xw + 36);

  uint64_t bits = 0, flag = 0;

#pragma unroll
  for (int ct = 0; ct < 4; ++ct) {
    // split current x chunk into hi/lo bf16 fragments
    short8 xh0, xl0, xh1, xl1;
#pragma unroll
    for (int i = 0; i < 4; ++i) {
      float hf;
      short h = bf16_hi(a0[i], hf); xh0[i]     = h; xl0[i]     = bf16_rn(a0[i] - hf);
      h = bf16_hi(a1[i], hf);       xh0[4 + i] = h; xl0[4 + i] = bf16_rn(a1[i] - hf);
      h = bf16_hi(a2[i], hf);       xh1[i]     = h; xl1[i]     = bf16_rn(a2[i] - hf);
      h = bf16_hi(a3[i], hf);       xh1[4 + i] = h; xl1[4 + i] = bf16_rn(a3[i] - hf);
    }
    if (ct < 3) {  // prefetch next ct's rows (hides HBM latency under MFMA+VALU)
      const float* p = xw + (size_t)(ct + 1) * 16 * 64;
      a0 = *(const f32x4*)(p);      a1 = *(const f32x4*)(p + 4);
      a2 = *(const f32x4*)(p + 32); a3 = *(const f32x4*)(p + 36);
    }

    // 3 row-tiles x (2 k-halves x 3 split terms) = 18 MFMA; lo.lo dropped.
    f32x4 acc[3];
#pragma unroll
    for (int rt = 0; rt < 3; ++rt) {
      f32x4 c = {0.f, 0.f, 0.f, 0.f};
      c = __builtin_amdgcn_mfma_f32_16x16x32_bf16(whi[rt][0], xh0, c, 0, 0, 0);
      c = __builtin_amdgcn_mfma_f32_16x16x32_bf16(whi[rt][1], xh1, c, 0, 0, 0);
      c = __builtin_amdgcn_mfma_f32_16x16x32_bf16(whi[rt][0], xl0, c, 0, 0, 0);
      c = __builtin_amdgcn_mfma_f32_16x16x32_bf16(whi[rt][1], xl1, c, 0, 0, 0);
      c = __builtin_amdgcn_mfma_f32_16x16x32_bf16(wlo[rt][0], xh0, c, 0, 0, 0);
      c = __builtin_amdgcn_mfma_f32_16x16x32_bf16(wlo[rt][1], xh1, c, 0, 0, 0);
      acc[rt] = c;
    }

    // per-lane partial masks for this ct's x-row (12 d's), then OR-butterfly
    uint64_t pb = 0, pf = 0;
#pragma unroll
    for (int rt = 0; rt < 3; ++rt) {
#pragma unroll
      for (int i = 0; i < 4; ++i) {
        const float t = acc[rt][i] - taub[rt][i];          // = z_hat - tau
        const int d = rt * 16 + q * 4 + i;
        pb |= (uint64_t)(t > 0.f ? 1u : 0u) << d;
        pf |= (uint64_t)(__builtin_fabsf(t) < kMarginB ? 1u : 0u) << d;
      }
    }
    pb |= __shfl_xor((unsigned long long)pb, 16);
    pb |= __shfl_xor((unsigned long long)pb, 32);
    pf |= __shfl_xor((unsigned long long)pf, 16);
    pf |= __shfl_xor((unsigned long long)pf, 32);
    if (ct == q) { bits = pb; flag = pf; }   // lane owns x-row == lane
  }

  // ---- Divergent fixup: bit-exact np-order recompute of flagged logits only
  //      (~7% of rows at 2e-3 margin; x row is L1/L2-hot).
  const float* __restrict__ xrow = x + (size_t)(rowbase + lane) * 64;
  while (flag) {
    const int d = __builtin_ctzll(flag);
    flag &= flag - 1;
    const float z = np_exact_dot(xrow, Wsel + d * 64) + bsel[d];
    const uint64_t m = 1ull << d;
    bits = (z > kTau) ? (bits | m) : (bits & ~m);
  }

  // ---- Tree walk (level 0 = MSB), LDS leaf gather, 16->2 FC.
  float o0 = fcb[0], o1 = fcb[1];
#pragma unroll
  for (int t = 0; t < 8; ++t) {
    int idx = 0;
#pragma unroll
    for (int l = 0; l < 6; ++l)
      idx = idx * 2 + (int)((bits >> (t * 6 + l)) & 1u);
    const f32x2 lv = lleaf[t * 64 + idx];
    o0 = fmaf(lv.x, fcw[2 * t], o0);
    o0 = fmaf(lv.y, fcw[2 * t + 1], o0);
    o1 = fmaf(lv.x, fcw[16 + 2 * t], o1);
    o1 = fmaf(lv.y, fcw[16 + 2 * t + 1], o1);
  }
  f32x2 r; r.x = o0; r.y = o1;
  ((f32x2*)out)[rowbase + lane] = r;
}

extern "C" void kernel_launch(void* const* d_in, const int* in_sizes, int n_in,
                              void* d_out, int out_size, void* d_ws, size_t ws_size,
                              hipStream_t stream) {
  (void)in_sizes; (void)n_in; (void)out_size; (void)d_ws; (void)ws_size;
  forest_mfma<<<kBlocks, 256, 0, stream>>>(
      (const float*)d_in[0],   // x
      (const float*)d_in[1],   // W_sel
      (const float*)d_in[2],   // b_sel
      (const float*)d_in[3],   // leaf_values
      (const float*)d_in[4],   // fc_w
      (const float*)d_in[5],   // fc_b
      (float*)d_out);
}

// Round 2
// 372.049 us; speedup vs baseline: 1.0607x; 1.0060x over previous
//
#include <hip/hip_runtime.h>
#include <hip/hip_bf16.h>
#include <stdint.h>

// NODE forest — MFMA path, round 2: latency-schedule polish.
// r1 verified: 48 per-row selector dots as bf16-split GEMM on the matrix pipe
// (hi+lo, 3 product terms), margin 2e-3 vs analytic worst-case ~1.3e-4 drift,
// np-exact fixup for near-threshold logits. PASS, absmax unchanged.
// r2 changes (schedule only, math untouched):
//   1. Issue the first 8 x-loads (ct0+ct1) as the FIRST instructions; the
//      W-fragment load+convert (~600 cyc incl L2 miss) and lleaf staging now
//      execute under x's ~900-cyc HBM latency instead of before it.
//   2. Prefetch 2-ahead in the ct loop (xa[ct+2]) -> 8 loads in flight steady
//      state (was 4) against ~900-cyc latency.
//   3. lleaf __syncthreads moved from prologue to just before the epilogue
//      gather (only the leaf-table read needs it).
// xa[4][4] is statically indexed under full unroll (no scratch, rule #20).
// Layouts (verified): D col=lane&15, row=(lane>>4)*4+reg; A/B 8 contiguous k
// at k=8*(lane>>4). C = W(48x64) . X^T(64x64rows); OR-butterfly (16,32)
// assembles each row's 48-bit mask on its owner lane.

typedef float f32x2 __attribute__((ext_vector_type(2)));
typedef float f32x4 __attribute__((ext_vector_type(4)));
typedef short short8 __attribute__((ext_vector_type(8)));

static constexpr int   kBlocks  = 4096;            // x4 waves x64 lanes = 1M rows
static constexpr float kTau     = 1.5f * 0x1p-24f; // f32 sigmoid dead-zone threshold
static constexpr float kMarginB = 2e-3f;           // ~15x analytic worst-case bf16-split drift

// Bit-exact replica of numpy's baseline-SIMD einsum f32 order (r5-verified).
__device__ __noinline__ float np_exact_dot(const float* __restrict__ xs,
                                           const float* __restrict__ w) {
#pragma clang fp contract(off)
  float s[4];
#pragma unroll
  for (int L = 0; L < 4; ++L) {
    float t = xs[12 + L] * w[12 + L];
    t = xs[8 + L] * w[8 + L] + t;
    t = xs[4 + L] * w[4 + L] + t;
    t = xs[0 + L] * w[0 + L] + t;
#pragma unroll
    for (int j = 1; j < 4; ++j) {
      const int o = 16 * j;
      t = xs[o + 12 + L] * w[o + 12 + L] + t;
      t = xs[o +  8 + L] * w[o +  8 + L] + t;
      t = xs[o +  4 + L] * w[o +  4 + L] + t;
      t = xs[o +  0 + L] * w[o +  0 + L] + t;
    }
    s[L] = t;
  }
  return (s[0] + s[1]) + (s[2] + s[3]);   // SSE3 hadd pairing
}

__device__ __forceinline__ short bf16_hi(float v, float& hf) {
  const __hip_bfloat16 h = __float2bfloat16(v);   // RNE
  hf = __bfloat162float(h);
  return __builtin_bit_cast(short, h);
}
__device__ __forceinline__ short bf16_rn(float v) {
  return __builtin_bit_cast(short, __float2bfloat16(v));
}

__global__ __launch_bounds__(256) void forest_mfma(
    const float* __restrict__ x,     // [B,64]
    const float* __restrict__ Wsel,  // [48,64]
    const float* __restrict__ bsel,  // [48]
    const float* __restrict__ leaf,  // [8,64,2]
    const float* __restrict__ fcw,   // [2,16]
    const float* __restrict__ fcb,   // [2]
    float* __restrict__ out)         // [B,2]
{
  const int lane = threadIdx.x & 63;
  const int wave = threadIdx.x >> 6;
  const int q    = lane >> 4;    // 0..3 : k-chunk group / d sub-offset
  const int r16  = lane & 15;    // 0..15
  const int rowbase = (blockIdx.x * 4 + wave) * 64;

  // ---- FIRST: issue x loads for ct0+ct1 (8 dwordx4 in flight). Everything
  //      below (lleaf stage, W load+convert, taub) runs under this latency.
  const float* xw = x + (size_t)(rowbase + r16) * 64 + q * 8;
  f32x4 xa[4][4];
#pragma unroll
  for (int c = 0; c < 2; ++c) {
    const float* p = xw + (size_t)c * 16 * 64;
    xa[c][0] = *(const f32x4*)(p);
    xa[c][1] = *(const f32x4*)(p + 4);
    xa[c][2] = *(const f32x4*)(p + 32);
    xa[c][3] = *(const f32x4*)(p + 36);
  }

  __shared__ f32x2 lleaf[512];
  ((f32x4*)lleaf)[threadIdx.x] = ((const f32x4*)leaf)[threadIdx.x];
  // (sync deferred to the epilogue — nothing reads lleaf until then)

  // ---- W fragments (A-operand), split hi/lo bf16. Lane: row=rt*16+r16,
  //      k = kh*32 + q*8 + i. L1/L2-broadcast; overlaps x HBM latency.
  short8 whi[3][2], wlo[3][2];
#pragma unroll
  for (int rt = 0; rt < 3; ++rt) {
#pragma unroll
    for (int kh = 0; kh < 2; ++kh) {
      const float* wp = Wsel + (rt * 16 + r16) * 64 + kh * 32 + q * 8;
      const f32x4 w0 = *(const f32x4*)wp;
      const f32x4 w1 = *(const f32x4*)(wp + 4);
      short8 hi, lo;
#pragma unroll
      for (int i = 0; i < 4; ++i) {
        float hf;
        short h = bf16_hi(w0[i], hf);
        hi[i] = h;     lo[i]     = bf16_rn(w0[i] - hf);
        h = bf16_hi(w1[i], hf);
        hi[4 + i] = h; lo[4 + i] = bf16_rn(w1[i] - hf);
      }
      whi[rt][kh] = hi; wlo[rt][kh] = lo;
    }
  }

  // ---- tau - bias for this lane's 12 d's: d = rt*16 + q*4 + i
  f32x4 taub[3];
#pragma unroll
  for (int rt = 0; rt < 3; ++rt) {
    const f32x4 bs = *(const f32x4*)(bsel + rt * 16 + q * 4);
    f32x4 t;
#pragma unroll
    for (int i = 0; i < 4; ++i) t[i] = kTau - bs[i];
    taub[rt] = t;
  }

  uint64_t bits = 0, flag = 0;

#pragma unroll
  for (int ct = 0; ct < 4; ++ct) {
    if (ct < 2) {  // prefetch 2-ahead: 8 loads in flight steady-state
      const float* p = xw + (size_t)(ct + 2) * 16 * 64;
      xa[ct + 2][0] = *(const f32x4*)(p);
      xa[ct + 2][1] = *(const f32x4*)(p + 4);
      xa[ct + 2][2] = *(const f32x4*)(p + 32);
      xa[ct + 2][3] = *(const f32x4*)(p + 36);
    }

    // split current x chunk into hi/lo bf16 fragments (waits on xa[ct] only)
    short8 xh0, xl0, xh1, xl1;
#pragma unroll
    for (int i = 0; i < 4; ++i) {
      float hf;
      short h = bf16_hi(xa[ct][0][i], hf); xh0[i]     = h; xl0[i]     = bf16_rn(xa[ct][0][i] - hf);
      h = bf16_hi(xa[ct][1][i], hf);       xh0[4 + i] = h; xl0[4 + i] = bf16_rn(xa[ct][1][i] - hf);
      h = bf16_hi(xa[ct][2][i], hf);       xh1[i]     = h; xl1[i]     = bf16_rn(xa[ct][2][i] - hf);
      h = bf16_hi(xa[ct][3][i], hf);       xh1[4 + i] = h; xl1[4 + i] = bf16_rn(xa[ct][3][i] - hf);
    }

    // 3 row-tiles x (2 k-halves x 3 split terms) = 18 MFMA; lo.lo dropped.
    f32x4 acc[3];
#pragma unroll
    for (int rt = 0; rt < 3; ++rt) {
      f32x4 c = {0.f, 0.f, 0.f, 0.f};
      c = __builtin_amdgcn_mfma_f32_16x16x32_bf16(whi[rt][0], xh0, c, 0, 0, 0);
      c = __builtin_amdgcn_mfma_f32_16x16x32_bf16(whi[rt][1], xh1, c, 0, 0, 0);
      c = __builtin_amdgcn_mfma_f32_16x16x32_bf16(whi[rt][0], xl0, c, 0, 0, 0);
      c = __builtin_amdgcn_mfma_f32_16x16x32_bf16(whi[rt][1], xl1, c, 0, 0, 0);
      c = __builtin_amdgcn_mfma_f32_16x16x32_bf16(wlo[rt][0], xh0, c, 0, 0, 0);
      c = __builtin_amdgcn_mfma_f32_16x16x32_bf16(wlo[rt][1], xh1, c, 0, 0, 0);
      acc[rt] = c;
    }

    // per-lane partial masks for this ct's x-row (12 d's), then OR-butterfly
    uint64_t pb = 0, pf = 0;
#pragma unroll
    for (int rt = 0; rt < 3; ++rt) {
#pragma unroll
      for (int i = 0; i < 4; ++i) {
        const float t = acc[rt][i] - taub[rt][i];          // = z_hat - tau
        const int d = rt * 16 + q * 4 + i;
        pb |= (uint64_t)(t > 0.f ? 1u : 0u) << d;
        pf |= (uint64_t)(__builtin_fabsf(t) < kMarginB ? 1u : 0u) << d;
      }
    }
    pb |= __shfl_xor((unsigned long long)pb, 16);
    pb |= __shfl_xor((unsigned long long)pb, 32);
    pf |= __shfl_xor((unsigned long long)pf, 16);
    pf |= __shfl_xor((unsigned long long)pf, 32);
    if (ct == q) { bits = pb; flag = pf; }   // lane owns x-row == lane
  }

  // ---- Divergent fixup: bit-exact np-order recompute of flagged logits only
  //      (~1.6e-3 per logit at 2e-3 margin; x row is L1/L2-hot).
  const float* __restrict__ xrow = x + (size_t)(rowbase + lane) * 64;
  while (flag) {
    const int d = __builtin_ctzll(flag);
    flag &= flag - 1;
    const float z = np_exact_dot(xrow, Wsel + d * 64) + bsel[d];
    const uint64_t m = 1ull << d;
    bits = (z > kTau) ? (bits | m) : (bits & ~m);
  }

  // ---- Tree walk (level 0 = MSB), LDS leaf gather, 16->2 FC.
  __syncthreads();   // lleaf staged in prologue; first read is below
  float o0 = fcb[0], o1 = fcb[1];
#pragma unroll
  for (int t = 0; t < 8; ++t) {
    int idx = 0;
#pragma unroll
    for (int l = 0; l < 6; ++l)
      idx = idx * 2 + (int)((bits >> (t * 6 + l)) & 1u);
    const f32x2 lv = lleaf[t * 64 + idx];
    o0 = fmaf(lv.x, fcw[2 * t], o0);
    o0 = fmaf(lv.y, fcw[2 * t + 1], o0);
    o1 = fmaf(lv.x, fcw[16 + 2 * t], o1);
    o1 = fmaf(lv.y, fcw[16 + 2 * t + 1], o1);
  }
  f32x2 r; r.x = o0; r.y = o1;
  ((f32x2*)out)[rowbase + lane] = r;
}

extern "C" void kernel_launch(void* const* d_in, const int* in_sizes, int n_in,
                              void* d_out, int out_size, void* d_ws, size_t ws_size,
                              hipStream_t stream) {
  (void)in_sizes; (void)n_in; (void)out_size; (void)d_ws; (void)ws_size;
  forest_mfma<<<kBlocks, 256, 0, stream>>>(
      (const float*)d_in[0],   // x
      (const float*)d_in[1],   // W_sel
      (const float*)d_in[2],   // b_sel
      (const float*)d_in[3],   // leaf_values
      (const float*)d_in[4],   // fc_w
      (const float*)d_in[5],   // fc_b
      (float*)d_out);
}